// Round 1
// baseline (1205.854 us; speedup 1.0000x reference)
//
#include <hip/hip_runtime.h>

// Problem constants (fixed by reference)
constexpr int kB    = 32;    // batch
constexpr int kKVH  = 8;     // kv heads
constexpr int kD    = 128;   // head dim
constexpr int kP    = 4096;  // cache positions
constexpr int kN    = 4096;  // QH*D
constexpr int kKN   = 1024;  // KVH*D
constexpr int kG    = 4;     // GQA group
constexpr int kNS   = 2;     // attention s-splits
constexpr int kSplit = kP / kNS;   // 2048
constexpr int kChunk = 64;         // s positions staged per iteration
constexpr int kStride = 130;       // LDS row stride (float2-friendly; 2-way bank alias = free)

// ---------------- Kernel 1: RMSNorm ----------------
__global__ __launch_bounds__(256) void rms_norm_kernel(const float* __restrict__ X,
                                                       float* __restrict__ xn) {
  int b = blockIdx.x;
  const float4* x4 = (const float4*)(X + (size_t)b * kN);
  float4* o4 = (float4*)(xn + (size_t)b * kN);
  float ss = 0.f;
  float4 v[4];
#pragma unroll
  for (int i = 0; i < 4; ++i) {
    v[i] = x4[threadIdx.x + i * 256];
    ss += v[i].x * v[i].x + v[i].y * v[i].y + v[i].z * v[i].z + v[i].w * v[i].w;
  }
#pragma unroll
  for (int m = 32; m; m >>= 1) ss += __shfl_xor(ss, m, 64);
  __shared__ float red[4];
  if ((threadIdx.x & 63) == 0) red[threadIdx.x >> 6] = ss;
  __syncthreads();
  float total = red[0] + red[1] + red[2] + red[3];
  float scale = rsqrtf(total * (1.f / kN));
#pragma unroll
  for (int i = 0; i < 4; ++i) {
    float4 r;
    r.x = v[i].x * scale; r.y = v[i].y * scale;
    r.z = v[i].z * scale; r.w = v[i].w * scale;
    o4[threadIdx.x + i * 256] = r;
  }
}

// ---------------- Kernel 2: QKV projection ----------------
// C[b][c] = sum_k xn[b][k] * W[c][k]; 6144 output cols (4096 q | 1024 k | 1024 v)
// block = 32 cols; thread = (col, batch-group of 4); K tiled by 64.
__global__ __launch_bounds__(256) void qkv_gemm_kernel(
    const float* __restrict__ xn, const float* __restrict__ Wq,
    const float* __restrict__ Wk, const float* __restrict__ Wv,
    float* __restrict__ qb, float* __restrict__ knew, float* __restrict__ vnew) {
  __shared__ float Wt[32 * 68];  // [col][k], pad 68 to spread banks
  __shared__ float Xt[32 * 68];  // [batch][k]
  int c0 = blockIdx.x * 32;
  const float* wsel;
  float* outp;
  int ostride;
  if (c0 < kN) {
    wsel = Wq + (size_t)c0 * kN; outp = qb + c0; ostride = kN;
  } else if (c0 < kN + kKN) {
    wsel = Wk + (size_t)(c0 - kN) * kN; outp = knew + (c0 - kN); ostride = kKN;
  } else {
    wsel = Wv + (size_t)(c0 - kN - kKN) * kN; outp = vnew + (c0 - kN - kKN); ostride = kKN;
  }
  int t = threadIdx.x;
  int cl = t & 31;   // local col
  int bg = t >> 5;   // 0..7 -> batches bg*4 .. bg*4+3
  int sr = t >> 3;   // staging row 0..31
  int sp = t & 7;    // staging part -> k offset sp*8
  float acc0 = 0.f, acc1 = 0.f, acc2 = 0.f, acc3 = 0.f;
  for (int k0 = 0; k0 < kN; k0 += 64) {
    __syncthreads();
    {
      const float4* wsrc = (const float4*)(wsel + (size_t)sr * kN + k0 + sp * 8);
      float4 w0 = wsrc[0], w1 = wsrc[1];
      const float4* xsrc = (const float4*)(xn + (size_t)sr * kN + k0 + sp * 8);
      float4 x0 = xsrc[0], x1 = xsrc[1];
      float4* wdst = (float4*)(Wt + sr * 68 + sp * 8);
      wdst[0] = w0; wdst[1] = w1;
      float4* xdst = (float4*)(Xt + sr * 68 + sp * 8);
      xdst[0] = x0; xdst[1] = x1;
    }
    __syncthreads();
    const float* wrow = Wt + cl * 68;
    const float* xr0 = Xt + (bg * 4 + 0) * 68;
    const float* xr1 = Xt + (bg * 4 + 1) * 68;
    const float* xr2 = Xt + (bg * 4 + 2) * 68;
    const float* xr3 = Xt + (bg * 4 + 3) * 68;
#pragma unroll
    for (int kk = 0; kk < 64; kk += 4) {
      float4 w4 = *(const float4*)(wrow + kk);
      float4 a0 = *(const float4*)(xr0 + kk);
      float4 a1 = *(const float4*)(xr1 + kk);
      float4 a2 = *(const float4*)(xr2 + kk);
      float4 a3 = *(const float4*)(xr3 + kk);
      acc0 += w4.x * a0.x + w4.y * a0.y + w4.z * a0.z + w4.w * a0.w;
      acc1 += w4.x * a1.x + w4.y * a1.y + w4.z * a1.z + w4.w * a1.w;
      acc2 += w4.x * a2.x + w4.y * a2.y + w4.z * a2.z + w4.w * a2.w;
      acc3 += w4.x * a3.x + w4.y * a3.y + w4.z * a3.z + w4.w * a3.w;
    }
  }
  outp[(size_t)(bg * 4 + 0) * ostride + cl] = acc0;
  outp[(size_t)(bg * 4 + 1) * ostride + cl] = acc1;
  outp[(size_t)(bg * 4 + 2) * ostride + cl] = acc2;
  outp[(size_t)(bg * 4 + 3) * ostride + cl] = acc3;
}

// ---------------- Kernel 3: attention partials over the cache ----------------
// Non-stabilized softmax => partial num/den are plain sums; block = (b, kv, s-split).
// wave w = GQA head g. Score phase: lanes over s. V phase: lanes over d (shfl-broadcast e).
__global__ __launch_bounds__(256) void attn_partial_kernel(
    const float* __restrict__ cK, const float* __restrict__ cV,
    const float* __restrict__ qb, float* __restrict__ num, float* __restrict__ den) {
  __shared__ float Kt[kChunk * kStride];
  __shared__ float Vt[kChunk * kStride];
  __shared__ float qs[kG * kD];
  int blk = blockIdx.x;
  int ss = blk & (kNS - 1);
  int kv = (blk >> 1) & (kKVH - 1);
  int b  = blk >> 4;
  int t = threadIdx.x;
  int w = t >> 6;   // wave = g
  int l = t & 63;
  for (int i = t; i < kG * kD; i += 256) {
    int g = i >> 7, d = i & 127;
    qs[i] = qb[(size_t)b * kN + (kv * kG + g) * kD + d];
  }
  const float* Kbase = cK + ((size_t)b * kP + (size_t)ss * kSplit) * kKN + kv * kD;
  const float* Vbase = cV + ((size_t)b * kP + (size_t)ss * kSplit) * kKN + kv * kD;
  float o0 = 0.f, o1 = 0.f, denp = 0.f;
  for (int c0 = 0; c0 < kSplit; c0 += kChunk) {
    __syncthreads();  // previous chunk fully consumed
    // stage K & V: 64 s x 128 d each; float4 global (coalesced 512B/row), float2 LDS writes
    for (int i = t; i < kChunk * 32; i += 256) {
      int s = i >> 5, dq = (i & 31) * 4;
      float4 k4 = *(const float4*)(Kbase + (size_t)(c0 + s) * kKN + dq);
      float4 v4 = *(const float4*)(Vbase + (size_t)(c0 + s) * kKN + dq);
      float* kd = Kt + s * kStride + dq;
      *(float2*)(kd)     = make_float2(k4.x, k4.y);
      *(float2*)(kd + 2) = make_float2(k4.z, k4.w);
      float* vd = Vt + s * kStride + dq;
      *(float2*)(vd)     = make_float2(v4.x, v4.y);
      *(float2*)(vd + 2) = make_float2(v4.z, v4.w);
    }
    __syncthreads();
    // scores: lane l = local s
    const float* krow = Kt + l * kStride;
    const float* qrow = qs + w * kD;
    float sc = 0.f;
#pragma unroll
    for (int d = 0; d < kD; d += 4) {
      float4 q4 = *(const float4*)(qrow + d);
      sc += q4.x * krow[d] + q4.y * krow[d + 1] + q4.z * krow[d + 2] + q4.w * krow[d + 3];
    }
    float e = __expf(sc);  // faithful non-stabilized exp (fp32-safe for this data)
    denp += e;
    // V accumulation: lane l owns d-pair (2l, 2l+1)
#pragma unroll 16
    for (int s = 0; s < kChunk; ++s) {
      float es = __shfl(e, s, 64);
      float2 v2 = *(const float2*)(Vt + s * kStride + l * 2);
      o0 += es * v2.x;
      o1 += es * v2.y;
    }
  }
  size_t base = ((((size_t)ss * kB + b) * kKVH + kv) * kG + w) * kD;
  num[base + l * 2]     = o0;
  num[base + l * 2 + 1] = o1;
#pragma unroll
  for (int m = 32; m; m >>= 1) denp += __shfl_xor(denp, m, 64);
  if (l == 0) den[(((size_t)ss * kB + b) * kKVH + kv) * kG + w] = denp;
}

// ---------------- Kernel 4: finalize (new token + divide) ----------------
__global__ __launch_bounds__(256) void attn_final_kernel(
    const float* __restrict__ qb, const float* __restrict__ knew,
    const float* __restrict__ vnew, const float* __restrict__ num,
    const float* __restrict__ den, float* __restrict__ out) {
  int blk = blockIdx.x;  // b*KVH + kv
  int kv = blk & (kKVH - 1);
  int b  = blk >> 3;
  int t = threadIdx.x;
  int g = t >> 6, l = t & 63;
  const float* qrow = qb + (size_t)b * kN + (kv * kG + g) * kD;
  const float* krow = knew + (size_t)b * kKN + kv * kD;
  const float* vrow = vnew + (size_t)b * kKN + kv * kD;
  float2 q2 = *(const float2*)(qrow + l * 2);
  float2 k2 = *(const float2*)(krow + l * 2);
  float dot = q2.x * k2.x + q2.y * k2.y;
#pragma unroll
  for (int m = 32; m; m >>= 1) dot += __shfl_xor(dot, m, 64);
  float e = __expf(dot);
  size_t p0 = (((size_t)0 * kB + b) * kKVH + kv) * kG + g;
  size_t p1 = (((size_t)1 * kB + b) * kKVH + kv) * kG + g;
  float dtot = den[p0] + den[p1] + e;
  float2 v2 = *(const float2*)(vrow + l * 2);
  float n0 = num[p0 * kD + l * 2]     + num[p1 * kD + l * 2]     + e * v2.x;
  float n1 = num[p0 * kD + l * 2 + 1] + num[p1 * kD + l * 2 + 1] + e * v2.y;
  float inv = 1.f / dtot;
  float* orow = out + (size_t)b * kN + (kv * kG + g) * kD;
  orow[l * 2]     = n0 * inv;
  orow[l * 2 + 1] = n1 * inv;
}

extern "C" void kernel_launch(void* const* d_in, const int* in_sizes, int n_in,
                              void* d_out, int out_size, void* d_ws, size_t ws_size,
                              hipStream_t stream) {
  const float* X  = (const float*)d_in[0];
  const float* Wq = (const float*)d_in[1];
  const float* Wk = (const float*)d_in[2];
  const float* Wv = (const float*)d_in[3];
  const float* cK = (const float*)d_in[4];
  const float* cV = (const float*)d_in[5];
  float* out = (float*)d_out;

  // workspace layout (floats): xn | qb | knew | vnew | num | den  (~2.37 MB)
  float* ws   = (float*)d_ws;
  float* xn   = ws;
  float* qb   = xn + (size_t)kB * kN;
  float* knew = qb + (size_t)kB * kN;
  float* vnew = knew + (size_t)kB * kKN;
  float* num  = vnew + (size_t)kB * kKN;
  float* den  = num + (size_t)kNS * kB * kKVH * kG * kD;

  hipLaunchKernelGGL(rms_norm_kernel, dim3(kB), dim3(256), 0, stream, X, xn);
  hipLaunchKernelGGL(qkv_gemm_kernel, dim3((kN + 2 * kKN) / 32), dim3(256), 0, stream,
                     xn, Wq, Wk, Wv, qb, knew, vnew);
  hipLaunchKernelGGL(attn_partial_kernel, dim3(kB * kKVH * kNS), dim3(256), 0, stream,
                     cK, cV, qb, num, den);
  hipLaunchKernelGGL(attn_final_kernel, dim3(kB * kKVH), dim3(256), 0, stream,
                     qb, knew, vnew, num, den, out);
}